// Round 1
// baseline (668.090 us; speedup 1.0000x reference)
//
#include <hip/hip_runtime.h>

#define NEGV (-1e9f)

constexpr int BN   = 64;
constexpr int S1   = 257;
constexpr int LEN  = 32;
constexpr int CH   = S1 * S1;          // 66049
constexpr int ROWS = LEN + 1;          // 33
constexpr int ABSZ = BN * ROWS * S1;   // 542784

// d_out layout (floats), reference return order: M, ll, a, b, ls, p, t
constexpr int OFF_M  = 0;
constexpr int OFF_LL = 64;
constexpr int OFF_A  = OFF_LL + ABSZ;
constexpr int OFF_B  = OFF_A + ABSZ;
constexpr int OFF_LS = OFF_B + ABSZ;
constexpr int OFF_P  = OFF_LS + 64;
constexpr int OFF_T  = OFF_P + ABSZ;

// workspace layout (floats)
constexpr int WS_CS = 0;               // 64*3*257 = 49344
constexpr int WS_M  = BN * 3 * S1;     // +64
constexpr int WS_QT = WS_M + 64;       // 3*66049

// ---------------------------------------------------------------- prep:
// C = log_softmax(logits, ch) ; cs[b,c,k] = prefix sum (cs[0]=0). Also ls->float.
__global__ __launch_bounds__(256) void k_prep(const float* __restrict__ logits,
                                              const int* __restrict__ ls,
                                              float* __restrict__ ws,
                                              float* __restrict__ out) {
  __shared__ float sC[3][256];
  const int b = blockIdx.x;
  const int tid = threadIdx.x;
  {
    float l0 = logits[(b*3+0)*256 + tid];
    float l1 = logits[(b*3+1)*256 + tid];
    float l2 = logits[(b*3+2)*256 + tid];
    float mm = fmaxf(l0, fmaxf(l1, l2));
    float lse = mm + __logf(__expf(l0-mm) + __expf(l1-mm) + __expf(l2-mm));
    sC[0][tid] = l0 - lse;
    sC[1][tid] = l1 - lse;
    sC[2][tid] = l2 - lse;
  }
  __syncthreads();
  const int w = tid >> 6, lane = tid & 63;
  if (w < 3) {
    float* cs = ws + WS_CS + b*771 + w*257;
    if (lane == 0) cs[0] = 0.f;
    float carry = 0.f;
    for (int t = 0; t < 4; ++t) {
      float v = sC[w][t*64 + lane];
      #pragma unroll
      for (int off = 1; off < 64; off <<= 1) {
        float o = __shfl_up(v, off);
        if (lane >= off) v += o;
      }
      cs[t*64 + lane + 1] = carry + v;
      carry += __shfl(v, 63);
    }
  }
  if (tid == 0) out[OFF_LS + b] = (float)ls[b];
}

// ---------------------------------------------------------------- Q transpose
__global__ __launch_bounds__(256) void k_qt(const float* __restrict__ Q,
                                            float* __restrict__ QT) {
  const int cj = blockIdx.x;           // c*257 + j
  const int c = cj / 257, j = cj - c*257;
  const float* Qc = Q + c*CH;
  float* QTc = QT + c*CH;
  for (int i = threadIdx.x; i < S1; i += 256)
    QTc[j*257 + i] = Qc[i*257 + j];    // coalesced writes, L2-hit strided reads
}

// ---------------------------------------------------------------- recursion:
// blocks 0..63 -> alpha(b), 64..127 -> beta(b). 1024 thr: 4 lanes per output row.
__global__ __launch_bounds__(1024) void k_rec(const float* __restrict__ Q,
                                              const float* __restrict__ QT,
                                              const int* __restrict__ pattern,
                                              const int* __restrict__ ls,
                                              float* __restrict__ ws,
                                              float* __restrict__ out) {
  __shared__ float csS[771];
  __shared__ float u4[264];    // alpha: u=la-cs ; beta: w=lb+cs  (4-way interleaved; slot 260 = idx 256)
  __shared__ float aux4[264];  // beta: lb copy (for row i=256)
  __shared__ float vS[257];    // la / lb
  __shared__ int patS[32];
  const int tid = threadIdx.x;
  const bool isBeta = (blockIdx.x >= BN);
  const int b = isBeta ? (blockIdx.x - BN) : blockIdx.x;
  for (int i = tid; i < 771; i += 1024) csS[i] = ws[WS_CS + b*771 + i];
  if (tid < 32) patS[tid] = pattern[tid];
  const int lsb = ls[b];
  const int jj = tid >> 2, q = tid & 3;
  float* outab = out + (isBeta ? OFF_B : OFF_A) + b * (ROWS * S1);

  if (!isBeta) {
    for (int i2 = tid; i2 < S1; i2 += 1024) {
      float v = (i2 == 0) ? 0.f : NEGV;
      vS[i2] = v;
      outab[i2] = v;                         // a row 0
    }
    __syncthreads();
    for (int step = 0; step < LEN; ++step) {
      const int c = patS[step];
      const float la256 = vS[256];
      if (tid < 256) u4[((tid & 63) << 2) | (tid >> 6)] = vS[tid] - csS[c*257 + tid];
      __syncthreads();
      const float* Qc = Q + c*CH;
      for (int row = jj; row < S1; row += 256) {
        const int lim = (row < 256) ? row : 256;   // valid i in [0,lim)
        const int lo = q << 6;
        int n = lim - lo; n = (n > 64) ? 64 : n;
        float m = -1e30f, s = 0.f;
        const float* qp = Qc + lo*257 + row;
        for (int kk = 0; kk < n; ++kk) {
          float x = qp[kk*257] + u4[(kk << 2) | q];
          float nm = fmaxf(m, x);
          s = s * __expf(m - nm) + __expf(x - nm);
          m = nm;
        }
        #pragma unroll
        for (int off = 1; off < 4; off <<= 1) {
          float om = __shfl_xor(m, off);
          float os = __shfl_xor(s, off);
          float nm = fmaxf(m, om);
          s = s * __expf(m - nm) + os * __expf(om - nm);
          m = nm;
        }
        float A = csS[c*257 + row] + m + __logf(s);    // -inf iff s==0 (row 0)
        float Bv = Qc[256*257 + row] + la256;          // i=256 path, always finite
        float h = fmaxf(A, Bv), l = fminf(A, Bv);
        float r = h + __logf(1.f + __expf(l - h));
        if (q == 0) {
          vS[row] = r;
          outab[(step + 1) * S1 + row] = r;
        }
      }
      __syncthreads();
    }
    if (tid == 0) {
      float Mv = vS[lsb];
      ws[WS_M + b] = Mv;
      out[OFF_M + b] = Mv;
    }
  } else {
    for (int i2 = tid; i2 < S1; i2 += 1024) {
      float v = (i2 == lsb) ? 0.f : NEGV;
      vS[i2] = v;
      outab[LEN * S1 + i2] = v;                // b row 32
    }
    __syncthreads();
    for (int step = LEN - 1; step >= 0; --step) {
      const int c = patS[step];
      if (tid < S1) {
        float lb = vS[tid];
        int slot = (tid < 256) ? (((tid & 63) << 2) | (tid >> 6)) : 260;
        u4[slot] = lb + csS[c*257 + tid];
        aux4[slot] = lb;
      }
      __syncthreads();
      const float* QTc = QT + c*CH;
      const float* Qc = Q + c*CH;
      for (int row = jj; row < S1; row += 256) {
        float m = -1e30f, s = 0.f;
        if (row < 256) {
          const int qlo = q << 6;
          int lo = (qlo > row + 1) ? qlo : (row + 1);
          int hi = qlo + 64; if (hi > 256) hi = 256;
          const float* qp = QTc + row;
          for (int j2 = lo; j2 < hi; ++j2) {
            float x = qp[j2*257] + u4[((j2 & 63) << 2) | q];
            float nm = fmaxf(m, x);
            s = s * __expf(m - nm) + __expf(x - nm);
            m = nm;
          }
          if (q == 3) {                        // j = 256 epilogue
            float x = QTc[256*257 + row] + u4[260];
            float nm = fmaxf(m, x);
            s = s * __expf(m - nm) + __expf(x - nm);
            m = nm;
          }
        } else {                               // row i = 256: P==0 for all j
          const int qlo = q << 6;
          const float* qp = Qc + 256*257 + qlo;
          for (int kk = 0; kk < 64; ++kk) {
            float x = qp[kk] + aux4[(kk << 2) | q];
            float nm = fmaxf(m, x);
            s = s * __expf(m - nm) + __expf(x - nm);
            m = nm;
          }
          if (q == 3) {
            float x = Qc[256*257 + 256] + aux4[260];
            float nm = fmaxf(m, x);
            s = s * __expf(m - nm) + __expf(x - nm);
            m = nm;
          }
        }
        #pragma unroll
        for (int off = 1; off < 4; off <<= 1) {
          float om = __shfl_xor(m, off);
          float os = __shfl_xor(s, off);
          float nm = fmaxf(m, om);
          s = s * __expf(m - nm) + os * __expf(om - nm);
          m = nm;
        }
        float r = m + __logf(s);
        if (row < 256) r -= csS[c*257 + row];
        if (q == 0) {
          vS[row] = r;
          outab[step * S1 + row] = r;
        }
      }
      __syncthreads();
    }
  }
}

// ---------------------------------------------------------------- ll & p
__global__ __launch_bounds__(256) void k_llp(const float* __restrict__ ws,
                                             float* __restrict__ out) {
  int idx = blockIdx.x * 256 + threadIdx.x;
  if (idx >= ABSZ) return;
  int b = idx / (ROWS * S1);
  float a = out[OFF_A + idx];
  float bb = out[OFF_B + idx];
  float ll = a + bb;
  __builtin_nontemporal_store(ll, out + OFF_LL + idx);
  __builtin_nontemporal_store(ll - ws[WS_M + b], out + OFF_P + idx);
}

// ---------------------------------------------------------------- t (541 MB)
__global__ __launch_bounds__(256) void k_t(const float* __restrict__ Q,
                                           const int* __restrict__ pattern,
                                           const float* __restrict__ ws,
                                           float* __restrict__ out) {
  __shared__ float r1[257], r2[257], c1[257], c2[257];
  const int bk = blockIdx.x;
  const int b = bk >> 5, k = bk & 31;
  const int c = pattern[k];
  const float Mb = ws[WS_M + b];
  const int tid = threadIdx.x;
  const float* cs = ws + WS_CS + b*771 + c*257;
  const float* ar = out + OFF_A + (b*ROWS + k) * S1;
  const float* br = out + OFF_B + (b*ROWS + k + 1) * S1;
  for (int i = tid; i < S1; i += 256) {
    float av = ar[i], cv = cs[i], bv = br[i];
    r1[i] = av - cv - Mb;                       // used when j > i  (P = cs[j]-cs[i])
    r2[i] = av - Mb + ((i == 256) ? 0.f : NEGV);// P = 0 (row 256) or NEG
    c1[i] = bv + cv;
    c2[i] = bv;
  }
  __syncthreads();
  const float* Qc = Q + c*CH;
  float* tb = out + OFF_T + (size_t)bk * CH;
  int i = 0, j = tid;                           // idx = i*257 + j, diagonal march
  for (int idx = tid; idx < CH; idx += 256) {
    float qv = Qc[idx];                          // Q[c,i,j] index == idx: coalesced
    float v = (j > i) ? (r1[i] + c1[j]) : (r2[i] + c2[j]);
    __builtin_nontemporal_store(qv + v, tb + idx);
    bool wr = (j == 0);
    i += wr ? 0 : 1;
    j = wr ? 256 : (j - 1);
  }
}

extern "C" void kernel_launch(void* const* d_in, const int* in_sizes, int n_in,
                              void* d_out, int out_size, void* d_ws, size_t ws_size,
                              hipStream_t stream) {
  const float* logits = (const float*)d_in[0];
  const float* Q      = (const float*)d_in[1];
  const int* pattern  = (const int*)d_in[2];
  const int* ls       = (const int*)d_in[3];
  float* out = (float*)d_out;
  float* ws  = (float*)d_ws;

  k_prep<<<BN, 256, 0, stream>>>(logits, ls, ws, out);
  k_qt<<<3*S1, 256, 0, stream>>>(Q, ws + WS_QT);
  k_rec<<<2*BN, 1024, 0, stream>>>(Q, ws + WS_QT, pattern, ls, ws, out);
  k_llp<<<(ABSZ + 255)/256, 256, 0, stream>>>(ws, out);
  k_t<<<BN*LEN, 256, 0, stream>>>(Q, pattern, ws, out);
}